// Round 7
// baseline (232.244 us; speedup 1.0000x reference)
//
#include <hip/hip_runtime.h>
#include <hip/hip_bf16.h>
#include <stdint.h>

// Problem constants (fixed by setup_inputs)
#define FCB 2            // codebooks
#define BB 16            // batch
#define NN 256           // tokens per (b)
#define EDIM 1024
#define CC 512           // channels per codebook
#define NE 4096          // prototypes per codebook
#define TOKENS (BB*FCB*NN)   // 8192
#define ROWS (FCB*NE)        // 8192 emb rows
#define OUT_LOSS (BB*NN*EDIM)   // 4194304 (also the element count for the mean)
#define OUT_IDX  (OUT_LOSS + 1)
#define MARGIN 0.15f     // rescore margin, v-units (score std ~1.0); ~75 sigma of bf16 noise

typedef __attribute__((ext_vector_type(8))) short bf16x8;    // MFMA A/B frag (4 VGPRs)
typedef __attribute__((ext_vector_type(16))) float f32x16;   // 32x32 MFMA C/D frag

// monotonic float<->uint mapping for packed argmax
__device__ __forceinline__ unsigned int ford(float v) {
    unsigned int u = __float_as_uint(v);
    return (u & 0x80000000u) ? ~u : (u | 0x80000000u);
}
__device__ __forceinline__ float unford(unsigned int u) {
    unsigned int b = (u & 0x80000000u) ? (u & 0x7fffffffu) : ~u;
    return __uint_as_float(b);
}

// ---------------------------------------------------------------------------
// ws layout:
//   [0]       bins      64 f32 + counter u32        (zeroed by K1)
//   [1024]    norm_sq   8192 f32  (32 KB)           (written by K1 norm blocks)
//   [65536]   cand      8192 tok x 64 slots x 2 u32 (4 MB)  top-2 per 64-col group
//   [+4MB]    z_hi      2*4096*512 bf16             (8 MB)  32-row-chunk packed
//   [+8MB]    e_hi      2*4096*512 bf16             (8 MB)
// Packed layout (R4-proven): chunk (f, R32, H) of 1024 B:
//   elem = ((f*128 + R32)*32 + H)*512 + q*256 + mm*8 + j
//   row = R32*32 + mm, k = H*16 + q*8 + j.
// One chunk == one wave-wide global_load_lds (64 lanes x 16 B), and the
// 32x32x16 A/B fragment read (m=lane&31, k=(lane>>5)*8+j) is exactly
// chunk_base + lane*16 -> conflict-free lane-linear.
// ---------------------------------------------------------------------------

// ---- K1: pack z/emb -> bf16 chunks; emb row norms; zero bins/counter -------
__global__ __launch_bounds__(256) void pack_init(
    const float* __restrict__ z, const float* __restrict__ emb,
    short* __restrict__ z_hi, short* __restrict__ e_hi,
    float* __restrict__ norm_sq, float* __restrict__ bins,
    unsigned int* __restrict__ counter)
{
    __shared__ float red[256];
    int bid = blockIdx.x;
    int tid = threadIdx.x;

    if (bid < 4096) {
        // ---- pack branch (R4-proven indexing) ----
        bool is_emb = (bid >= 2048);
        const float* src; short* hi; int RS, FRO, FCO;
        if (!is_emb) { src = z;   hi = z_hi; RS = EDIM; FRO = 0;  FCO = CC; }
        else         { src = emb; hi = e_hi; RS = CC;   FRO = NE; FCO = 0; }
        int gid = (bid & 2047) * 256 + tid;       // [0, 524288)
        int chunk = gid >> 6;
        int mm = gid & 31;
        int q  = (gid >> 5) & 1;
        int f  = chunk >> 12;
        int R32 = (chunk >> 5) & 127;
        int H  = chunk & 31;
        int row = R32 * 32 + mm;
        const float* s = src + (size_t)(f * FRO + row) * RS + f * FCO + H * 16 + q * 8;
        float4 v0 = *(const float4*)s;
        float4 v1 = *(const float4*)(s + 4);
        float vv[8] = {v0.x, v0.y, v0.z, v0.w, v1.x, v1.y, v1.z, v1.w};
        bf16x8 h8;
        #pragma unroll
        for (int j = 0; j < 8; ++j) {
            __hip_bfloat16 hb = __float2bfloat16(vv[j]);
            h8[j] = *(short*)&hb;
        }
        *(bf16x8*)(hi + (size_t)gid * 8) = h8;
    } else {
        // ---- norm branch: 512 blocks x 16 emb rows, no atomics ----
        int nb = bid - 4096;                      // [0, 512)
        if (nb == 0 && tid < 65) {
            if (tid < 64) bins[tid] = 0.0f;
            else          *counter = 0u;
        }
        int row_l = tid >> 4;                     // 0..15
        int seg   = tid & 15;                     // 0..15, 32 floats each
        int r = nb * 16 + row_l;                  // global emb row
        const float* p = emb + (size_t)r * CC + seg * 32;
        float ss = 0.f;
        #pragma unroll
        for (int h = 0; h < 8; ++h) {
            float4 v = *(const float4*)(p + h * 4);
            ss = fmaf(v.x, v.x, fmaf(v.y, v.y, fmaf(v.z, v.z, fmaf(v.w, v.w, ss))));
        }
        red[tid] = ss;
        __syncthreads();
        if (tid < 16) {
            float t = 0.f;
            #pragma unroll
            for (int k = 0; k < 16; ++k) t += red[tid * 16 + k];
            norm_sq[nb * 16 + tid] = t;
        }
    }
}

// ---- K2: 1-product bf16 MFMA GEMM (32x32x16, BK=64) + top-2 selection ------
// 128x128 block, 4 waves (2x2); wave = 64x64 = 2x2 tiles of 32x32.
__global__ __launch_bounds__(256, 3) void gemm_sel(
    const short* __restrict__ zh, const short* __restrict__ eh,
    const float* __restrict__ norm_sq, unsigned int* __restrict__ cand)
{
    __shared__ char smem[32768];      // A 16K | B 16K, chunk c at c*1024
    const int f  = blockIdx.z;
    const int t0 = blockIdx.y * 128;  // token base within codebook
    const int m0 = blockIdx.x * 128;  // proto base within codebook
    const int tid  = threadIdx.x;
    const int wave = tid >> 6, lane = tid & 63;
    const int wm = wave & 1, wn = wave >> 1;

    f32x16 acc[2][2] = {};

    for (int step = 0; step < 8; ++step) {
        __syncthreads();              // previous compute done before overwrite
        // 32 chunks of 1 KB per step: A (c<16: rl=c>>2,h=c&3), B (c>=16)
        #pragma unroll
        for (int i = 0; i < 8; ++i) {
            int c = wave * 8 + i;
            bool isA = (c < 16);
            int cl = c & 15;
            int rl = cl >> 2, h = cl & 3;
            int R32 = (isA ? (t0 >> 5) : (m0 >> 5)) + rl;
            int H = step * 4 + h;
            const short* g = (isA ? zh : eh)
                + (((size_t)f * 128 + R32) * 32 + H) * 512 + (size_t)lane * 8;
            __builtin_amdgcn_global_load_lds(
                (const __attribute__((address_space(1))) void*)g,
                (__attribute__((address_space(3))) void*)(smem + c * 1024),
                16, 0, 0);
        }
        __syncthreads();              // staged data visible to all waves

        #pragma unroll
        for (int h = 0; h < 4; ++h) {
            bf16x8 a0 = *(const bf16x8*)(smem + ((wm*2 + 0)*4 + h) * 1024 + lane * 16);
            bf16x8 a1 = *(const bf16x8*)(smem + ((wm*2 + 1)*4 + h) * 1024 + lane * 16);
            bf16x8 b0 = *(const bf16x8*)(smem + 16384 + ((wn*2 + 0)*4 + h) * 1024 + lane * 16);
            bf16x8 b1 = *(const bf16x8*)(smem + 16384 + ((wn*2 + 1)*4 + h) * 1024 + lane * 16);
            acc[0][0] = __builtin_amdgcn_mfma_f32_32x32x16_bf16(a0, b0, acc[0][0], 0, 0, 0);
            acc[0][1] = __builtin_amdgcn_mfma_f32_32x32x16_bf16(a0, b1, acc[0][1], 0, 0, 0);
            acc[1][0] = __builtin_amdgcn_mfma_f32_32x32x16_bf16(a1, b0, acc[1][0], 0, 0, 0);
            acc[1][1] = __builtin_amdgcn_mfma_f32_32x32x16_bf16(a1, b1, acc[1][1], 0, 0, 0);
        }
    }

    // ---- selection epilogue: per token, top-2 over this wave's 64 cols ----
    // 32x32 C/D layout (R4-verified): col = lane&31,
    // row = (r&3) + 8*(r>>2) + 4*(lane>>5)
    float inm[2]; unsigned ccode[2];
    #pragma unroll
    for (int j = 0; j < 2; ++j) {
        int col = j * 32 + (lane & 31);           // [0,64) within wave group
        ccode[j] = (unsigned)(col ^ 63);
        inm[j] = rsqrtf(norm_sq[f * NE + m0 + wn * 64 + col]);
    }

    #pragma unroll
    for (int i = 0; i < 2; ++i) {
        #pragma unroll
        for (int r = 0; r < 16; ++r) {
            float w0 = acc[i][0][r] * inm[0];
            float w1 = acc[i][1][r] * inm[1];
            unsigned pa = (ford(w0) & 0xFFFFFFC0u) | ccode[0];
            unsigned pb = (ford(w1) & 0xFFFFFFC0u) | ccode[1];
            unsigned p1 = pa > pb ? pa : pb;
            unsigned p2 = pa > pb ? pb : pa;
            // merge top-2 across the 32 lanes of this half-wave
            #pragma unroll
            for (int off = 16; off; off >>= 1) {
                unsigned q1 = __shfl_down(p1, off, 32);
                unsigned q2 = __shfl_down(p2, off, 32);
                if (q1 > p1) { unsigned t = p1; p1 = q1; p2 = (t > q2) ? t : q2; }
                else         { p2 = (p2 > q1) ? p2 : q1; }
            }
            if ((lane & 31) == 0) {
                int row = (r & 3) + 8 * (r >> 2) + 4 * (lane >> 5);
                int u = t0 + wm * 64 + i * 32 + row;
                int b = u >> 8, n = u & 255;
                int gt = ((b * FCB + f) << 8) + n;   // global token id (b,f,n)
                int s = (blockIdx.x << 1) | wn;      // slot covers cols s*64..
                uint2 val; val.x = p1; val.y = p2;
                *(uint2*)(cand + ((size_t)gt << 7) + (s << 1)) = val;
            }
        }
    }
}

// ---- K3: rescore + outputs + last-block loss finalize ----------------------
__global__ __launch_bounds__(256) void rescore_epilogue(
    const float* __restrict__ z, const float* __restrict__ emb,
    const unsigned int* __restrict__ cand,
    float* __restrict__ out, float* __restrict__ bins,
    unsigned int* __restrict__ counter)
{
    __shared__ float lred[4];
    __shared__ int last;
    int wave = threadIdx.x >> 6;
    int t = blockIdx.x * 4 + wave;                 // global token (b,f,n)
    int lane = threadIdx.x & 63;
    int n = t & 255;
    int f = (t >> 8) & 1;
    int b = t >> 9;
    const float* zrow = z + ((size_t)(b*NN + n))*EDIM + f*CC;
    float4 za = *(const float4*)(zrow + lane * 8);
    float4 zb = *(const float4*)(zrow + lane * 8 + 4);

    // 128 candidates: lane reads slot s == lane (2 packed u32)
    uint2 cc = *(const uint2*)(cand + ((size_t)t << 7) + (lane << 1));
    unsigned c1 = cc.x, c2 = cc.y;

    unsigned m1 = (c1 > c2) ? c1 : c2;
    #pragma unroll
    for (int off = 32; off; off >>= 1) {
        unsigned o = __shfl_xor(m1, off);
        if (o > m1) m1 = o;
    }
    float thr = unford(m1) - MARGIN;

    unsigned long long bestp = 0ull;
    #pragma unroll
    for (int rnd = 0; rnd < 2; ++rnd) {
        unsigned u = rnd ? c2 : c1;
        float v = unford(u);
        unsigned long long mask = __ballot(v > thr);
        while (mask) {
            int src = __ffsll((long long)mask) - 1;
            mask &= mask - 1;
            unsigned cu = __shfl(u, src);
            int idx = (src << 6) | ((int)(cu & 63u) ^ 63);   // proto index [0,4096)
            const float* er = emb + ((size_t)(f * NE + idx)) * CC;
            float4 ea = *(const float4*)(er + lane * 8);
            float4 eb = *(const float4*)(er + lane * 8 + 4);
            float d  = za.x*ea.x + za.y*ea.y + za.z*ea.z + za.w*ea.w
                     + zb.x*eb.x + zb.y*eb.y + zb.z*eb.z + zb.w*eb.w;
            float se = ea.x*ea.x + ea.y*ea.y + ea.z*ea.z + ea.w*ea.w
                     + eb.x*eb.x + eb.y*eb.y + eb.z*eb.z + eb.w*eb.w;
            #pragma unroll
            for (int off = 32; off; off >>= 1) {
                d  += __shfl_xor(d, off);
                se += __shfl_xor(se, off);
            }
            float vex = d / fmaxf(sqrtf(se), 1e-12f);        // exact score
            unsigned long long pex = ((unsigned long long)ford(vex) << 32)
                                   | (unsigned int)(~(unsigned int)idx);
            if (pex > bestp) bestp = pex;
        }
    }
    int idxb = (int)(~(unsigned int)bestp);    // exact argmax (tie -> lower idx)

    // ---- output: z_q gather (codebook-0 row, faithful quirk) + loss -------
    const float* er0 = emb + (size_t)idxb * CC;
    float4 ea = *(const float4*)(er0 + lane * 8);
    float4 eb = *(const float4*)(er0 + lane * 8 + 4);
    float se0 = ea.x*ea.x + ea.y*ea.y + ea.z*ea.z + ea.w*ea.w
              + eb.x*eb.x + eb.y*eb.y + eb.z*eb.z + eb.w*eb.w;
    #pragma unroll
    for (int off = 32; off; off >>= 1) se0 += __shfl_xor(se0, off);
    float inm0 = 1.0f / fmaxf(sqrtf(se0), 1e-12f);
    float* orow = out + ((size_t)(b*NN + n))*EDIM + f*CC;
    ea.x *= inm0; ea.y *= inm0; ea.z *= inm0; ea.w *= inm0;
    eb.x *= inm0; eb.y *= inm0; eb.z *= inm0; eb.w *= inm0;
    *(float4*)(orow + lane * 8) = ea;
    *(float4*)(orow + lane * 8 + 4) = eb;
    float s1 = za.x*za.x + za.y*za.y + za.z*za.z + za.w*za.w
             + zb.x*zb.x + zb.y*zb.y + zb.z*zb.z + zb.w*zb.w;
    float s2 = za.x*ea.x + za.y*ea.y + za.z*ea.z + za.w*ea.w
             + zb.x*eb.x + zb.y*eb.y + zb.z*eb.z + zb.w*eb.w;
    #pragma unroll
    for (int off = 32; off; off >>= 1) {
        s1 += __shfl_xor(s1, off);
        s2 += __shfl_xor(s2, off);
    }
    float tokloss = 0.f;
    if (lane == 0) {
        float cosv = s2 / fmaxf(sqrtf(s1), 1e-12f);   // zn . z_q
        tokloss = 2.0f - 2.0f * cosv;
        out[OUT_IDX + t] = (float)idxb;               // indices read back as float
    }

    // ---- loss finalize: 64 bins + device-scope counter, last block sums ----
    if (lane == 0) lred[wave] = tokloss;
    if (threadIdx.x == 0) last = 0;
    __syncthreads();
    if (threadIdx.x == 0) {
        float part = lred[0] + lred[1] + lred[2] + lred[3];
        atomicAdd(&bins[blockIdx.x & 63], part);
        __threadfence();
        unsigned old = atomicAdd(counter, 1u);
        if (old == (unsigned)(TOKENS/4 - 1)) last = 1;
    }
    __syncthreads();
    if (last && threadIdx.x < 64) {
        float v = atomicAdd(&bins[threadIdx.x], 0.0f);   // coherent RMW read
        #pragma unroll
        for (int off = 32; off; off >>= 1) v += __shfl_down(v, off);
        if (threadIdx.x == 0) out[OUT_LOSS] = v * (1.25f / (float)OUT_LOSS);
    }
}

extern "C" void kernel_launch(void* const* d_in, const int* in_sizes, int n_in,
                              void* d_out, int out_size, void* d_ws, size_t ws_size,
                              hipStream_t stream) {
    const float* z   = (const float*)d_in[0];
    const float* emb = (const float*)d_in[1];
    float* out = (float*)d_out;

    char* ws = (char*)d_ws;
    float* bins = (float*)ws;                                       // 256 B
    unsigned int* counter = (unsigned int*)(ws + 256);              // 4 B
    float* norm_sq = (float*)(ws + 1024);                           // 32 KB
    unsigned int* cand = (unsigned int*)(ws + 65536);               // 4 MB
    short* z_hi = (short*)(ws + 65536 + (size_t)4*1024*1024);       // 8 MB
    short* e_hi = z_hi + (size_t)FCB * NE * CC;                     // 8 MB
    // ws needed: ~20.1 MB

    pack_init<<<4608, 256, 0, stream>>>(z, emb, z_hi, e_hi, norm_sq, bins, counter);
    gemm_sel<<<dim3(NE/128, NE/128, FCB), 256, 0, stream>>>(z_hi, e_hi, norm_sq, cand);
    rescore_epilogue<<<TOKENS/4, 256, 0, stream>>>(z, emb, cand, out, bins, counter);
}

// Round 8
// 161.461 us; speedup vs baseline: 1.4384x; 1.4384x over previous
//
#include <hip/hip_runtime.h>
#include <hip/hip_bf16.h>
#include <stdint.h>

// Problem constants (fixed by setup_inputs)
#define FCB 2            // codebooks
#define BB 16            // batch
#define NN 256           // tokens per (b)
#define EDIM 1024
#define CC 512           // channels per codebook
#define NE 4096          // prototypes per codebook
#define TOKENS (BB*FCB*NN)   // 8192
#define ROWS (FCB*NE)        // 8192 emb rows
#define OUT_LOSS (BB*NN*EDIM)   // 4194304 (also the element count for the mean)
#define OUT_IDX  (OUT_LOSS + 1)
#define MARGIN 0.15f     // rescore margin, v-units (score std ~1.0); ~75 sigma of bf16 noise

typedef __attribute__((ext_vector_type(8))) short bf16x8;    // MFMA A/B frag (4 VGPRs)
typedef __attribute__((ext_vector_type(16))) float f32x16;   // 32x32 MFMA C/D frag

// monotonic float<->uint mapping for packed argmax
__device__ __forceinline__ unsigned int ford(float v) {
    unsigned int u = __float_as_uint(v);
    return (u & 0x80000000u) ? ~u : (u | 0x80000000u);
}
__device__ __forceinline__ float unford(unsigned int u) {
    unsigned int b = (u & 0x80000000u) ? (u & 0x7fffffffu) : ~u;
    return __uint_as_float(b);
}

// ---------------------------------------------------------------------------
// ws layout:
//   [0]       norm_sq   8192 f32  (32 KB)          (written by K1 norm blocks)
//   [32768]   loss_tok  8192 f32  (32 KB)
//   [65536]   cand      8192 tok x 64 slots x 2 u32 (4 MB) top-2 per 64-col group
//   [+4MB]    z_hi      2*4096*512 bf16             (8 MB) 32-row-chunk packed
//   [+8MB]    e_hi      2*4096*512 bf16             (8 MB)
// Packed layout (R4-proven): chunk (f, R32, H) of 1024 B:
//   elem = ((f*128 + R32)*32 + H)*512 + q*256 + mm*8 + j
//   row = R32*32 + mm, k = H*16 + q*8 + j.
// One chunk == one wave-wide global_load_lds (64 lanes x 16 B), and the
// 32x32x16 A/B fragment read (m=lane&31, k=(lane>>5)*8+j) is exactly
// chunk_base + lane*16 -> conflict-free lane-linear.
//
// NOTE (R7 lesson): no device-scope fences / completion counters inside
// output-writing kernels — the per-block write drain cost ~90 µs. Loss is
// finalized by a separate 1-block kernel instead.
// ---------------------------------------------------------------------------

// ---- K1: pack z/emb -> bf16 chunks; emb row norms --------------------------
__global__ __launch_bounds__(256) void pack_init(
    const float* __restrict__ z, const float* __restrict__ emb,
    short* __restrict__ z_hi, short* __restrict__ e_hi,
    float* __restrict__ norm_sq)
{
    __shared__ float red[256];
    int bid = blockIdx.x;
    int tid = threadIdx.x;

    if (bid < 4096) {
        // ---- pack branch (R4-proven indexing) ----
        bool is_emb = (bid >= 2048);
        const float* src; short* hi; int RS, FRO, FCO;
        if (!is_emb) { src = z;   hi = z_hi; RS = EDIM; FRO = 0;  FCO = CC; }
        else         { src = emb; hi = e_hi; RS = CC;   FRO = NE; FCO = 0; }
        int gid = (bid & 2047) * 256 + tid;       // [0, 524288)
        int chunk = gid >> 6;
        int mm = gid & 31;
        int q  = (gid >> 5) & 1;
        int f  = chunk >> 12;
        int R32 = (chunk >> 5) & 127;
        int H  = chunk & 31;
        int row = R32 * 32 + mm;
        const float* s = src + (size_t)(f * FRO + row) * RS + f * FCO + H * 16 + q * 8;
        float4 v0 = *(const float4*)s;
        float4 v1 = *(const float4*)(s + 4);
        float vv[8] = {v0.x, v0.y, v0.z, v0.w, v1.x, v1.y, v1.z, v1.w};
        bf16x8 h8;
        #pragma unroll
        for (int j = 0; j < 8; ++j) {
            __hip_bfloat16 hb = __float2bfloat16(vv[j]);
            h8[j] = *(short*)&hb;
        }
        *(bf16x8*)(hi + (size_t)gid * 8) = h8;
    } else {
        // ---- norm branch: 512 blocks x 16 emb rows, no atomics ----
        int nb = bid - 4096;                      // [0, 512)
        int row_l = tid >> 4;                     // 0..15
        int seg   = tid & 15;                     // 0..15, 32 floats each
        int r = nb * 16 + row_l;                  // global emb row
        const float* p = emb + (size_t)r * CC + seg * 32;
        float ss = 0.f;
        #pragma unroll
        for (int h = 0; h < 8; ++h) {
            float4 v = *(const float4*)(p + h * 4);
            ss = fmaf(v.x, v.x, fmaf(v.y, v.y, fmaf(v.z, v.z, fmaf(v.w, v.w, ss))));
        }
        red[tid] = ss;
        __syncthreads();
        if (tid < 16) {
            float t = 0.f;
            #pragma unroll
            for (int k = 0; k < 16; ++k) t += red[tid * 16 + k];
            norm_sq[nb * 16 + tid] = t;
        }
    }
}

// ---- K2: 1-product bf16 MFMA GEMM (32x32x16, BK=64) + top-2 selection ------
// 128x128 block, 4 waves (2x2); wave = 64x64 = 2x2 tiles of 32x32.
__global__ __launch_bounds__(256, 3) void gemm_sel(
    const short* __restrict__ zh, const short* __restrict__ eh,
    const float* __restrict__ norm_sq, unsigned int* __restrict__ cand)
{
    __shared__ char smem[32768];      // A 16K | B 16K, chunk c at c*1024
    const int f  = blockIdx.z;
    const int t0 = blockIdx.y * 128;  // token base within codebook
    const int m0 = blockIdx.x * 128;  // proto base within codebook
    const int tid  = threadIdx.x;
    const int wave = tid >> 6, lane = tid & 63;
    const int wm = wave & 1, wn = wave >> 1;

    f32x16 acc[2][2] = {};

    for (int step = 0; step < 8; ++step) {
        __syncthreads();              // previous compute done before overwrite
        // 32 chunks of 1 KB per step: A (c<16: rl=c>>2,h=c&3), B (c>=16)
        #pragma unroll
        for (int i = 0; i < 8; ++i) {
            int c = wave * 8 + i;
            bool isA = (c < 16);
            int cl = c & 15;
            int rl = cl >> 2, h = cl & 3;
            int R32 = (isA ? (t0 >> 5) : (m0 >> 5)) + rl;
            int H = step * 4 + h;
            const short* g = (isA ? zh : eh)
                + (((size_t)f * 128 + R32) * 32 + H) * 512 + (size_t)lane * 8;
            __builtin_amdgcn_global_load_lds(
                (const __attribute__((address_space(1))) void*)g,
                (__attribute__((address_space(3))) void*)(smem + c * 1024),
                16, 0, 0);
        }
        __syncthreads();              // staged data visible to all waves

        #pragma unroll
        for (int h = 0; h < 4; ++h) {
            bf16x8 a0 = *(const bf16x8*)(smem + ((wm*2 + 0)*4 + h) * 1024 + lane * 16);
            bf16x8 a1 = *(const bf16x8*)(smem + ((wm*2 + 1)*4 + h) * 1024 + lane * 16);
            bf16x8 b0 = *(const bf16x8*)(smem + 16384 + ((wn*2 + 0)*4 + h) * 1024 + lane * 16);
            bf16x8 b1 = *(const bf16x8*)(smem + 16384 + ((wn*2 + 1)*4 + h) * 1024 + lane * 16);
            acc[0][0] = __builtin_amdgcn_mfma_f32_32x32x16_bf16(a0, b0, acc[0][0], 0, 0, 0);
            acc[0][1] = __builtin_amdgcn_mfma_f32_32x32x16_bf16(a0, b1, acc[0][1], 0, 0, 0);
            acc[1][0] = __builtin_amdgcn_mfma_f32_32x32x16_bf16(a1, b0, acc[1][0], 0, 0, 0);
            acc[1][1] = __builtin_amdgcn_mfma_f32_32x32x16_bf16(a1, b1, acc[1][1], 0, 0, 0);
        }
    }

    // ---- selection epilogue: per token, top-2 over this wave's 64 cols ----
    // 32x32 C/D layout (R4-verified): col = lane&31,
    // row = (r&3) + 8*(r>>2) + 4*(lane>>5)
    float inm[2]; unsigned ccode[2];
    #pragma unroll
    for (int j = 0; j < 2; ++j) {
        int col = j * 32 + (lane & 31);           // [0,64) within wave group
        ccode[j] = (unsigned)(col ^ 63);
        inm[j] = rsqrtf(norm_sq[f * NE + m0 + wn * 64 + col]);
    }

    #pragma unroll
    for (int i = 0; i < 2; ++i) {
        #pragma unroll
        for (int r = 0; r < 16; ++r) {
            float w0 = acc[i][0][r] * inm[0];
            float w1 = acc[i][1][r] * inm[1];
            unsigned pa = (ford(w0) & 0xFFFFFFC0u) | ccode[0];
            unsigned pb = (ford(w1) & 0xFFFFFFC0u) | ccode[1];
            unsigned p1 = pa > pb ? pa : pb;
            unsigned p2 = pa > pb ? pb : pa;
            // merge top-2 across the 32 lanes of this half-wave
            #pragma unroll
            for (int off = 16; off; off >>= 1) {
                unsigned q1 = __shfl_down(p1, off, 32);
                unsigned q2 = __shfl_down(p2, off, 32);
                if (q1 > p1) { unsigned t = p1; p1 = q1; p2 = (t > q2) ? t : q2; }
                else         { p2 = (p2 > q1) ? p2 : q1; }
            }
            if ((lane & 31) == 0) {
                int row = (r & 3) + 8 * (r >> 2) + 4 * (lane >> 5);
                int u = t0 + wm * 64 + i * 32 + row;
                int b = u >> 8, n = u & 255;
                int gt = ((b * FCB + f) << 8) + n;   // global token id (b,f,n)
                int s = (blockIdx.x << 1) | wn;      // slot covers cols s*64..
                uint2 val; val.x = p1; val.y = p2;
                *(uint2*)(cand + ((size_t)gt << 7) + (s << 1)) = val;
            }
        }
    }
}

// ---- K3: rescore + outputs + per-token loss (NO atomics, NO fences) --------
__global__ __launch_bounds__(256) void rescore_epilogue(
    const float* __restrict__ z, const float* __restrict__ emb,
    const unsigned int* __restrict__ cand,
    float* __restrict__ out, float* __restrict__ loss_tok)
{
    int t = blockIdx.x * 4 + (threadIdx.x >> 6);   // global token (b,f,n)
    int lane = threadIdx.x & 63;
    int n = t & 255;
    int f = (t >> 8) & 1;
    int b = t >> 9;
    const float* zrow = z + ((size_t)(b*NN + n))*EDIM + f*CC;
    float4 za = *(const float4*)(zrow + lane * 8);
    float4 zb = *(const float4*)(zrow + lane * 8 + 4);

    // 128 candidates: lane reads slot s == lane (2 packed u32)
    uint2 cc = *(const uint2*)(cand + ((size_t)t << 7) + (lane << 1));
    unsigned c1 = cc.x, c2 = cc.y;

    unsigned m1 = (c1 > c2) ? c1 : c2;
    #pragma unroll
    for (int off = 32; off; off >>= 1) {
        unsigned o = __shfl_xor(m1, off);
        if (o > m1) m1 = o;
    }
    float thr = unford(m1) - MARGIN;

    unsigned long long bestp = 0ull;
    #pragma unroll
    for (int rnd = 0; rnd < 2; ++rnd) {
        unsigned u = rnd ? c2 : c1;
        float v = unford(u);
        unsigned long long mask = __ballot(v > thr);
        while (mask) {
            int src = __ffsll((long long)mask) - 1;
            mask &= mask - 1;
            unsigned cu = __shfl(u, src);
            int idx = (src << 6) | ((int)(cu & 63u) ^ 63);   // proto index [0,4096)
            const float* er = emb + ((size_t)(f * NE + idx)) * CC;
            float4 ea = *(const float4*)(er + lane * 8);
            float4 eb = *(const float4*)(er + lane * 8 + 4);
            float d  = za.x*ea.x + za.y*ea.y + za.z*ea.z + za.w*ea.w
                     + zb.x*eb.x + zb.y*eb.y + zb.z*eb.z + zb.w*eb.w;
            float se = ea.x*ea.x + ea.y*ea.y + ea.z*ea.z + ea.w*ea.w
                     + eb.x*eb.x + eb.y*eb.y + eb.z*eb.z + eb.w*eb.w;
            #pragma unroll
            for (int off = 32; off; off >>= 1) {
                d  += __shfl_xor(d, off);
                se += __shfl_xor(se, off);
            }
            float vex = d / fmaxf(sqrtf(se), 1e-12f);        // exact score
            unsigned long long pex = ((unsigned long long)ford(vex) << 32)
                                   | (unsigned int)(~(unsigned int)idx);
            if (pex > bestp) bestp = pex;
        }
    }
    int idxb = (int)(~(unsigned int)bestp);    // exact argmax (tie -> lower idx)

    // ---- output: z_q gather (codebook-0 row, faithful quirk) + loss -------
    const float* er0 = emb + (size_t)idxb * CC;
    float4 ea = *(const float4*)(er0 + lane * 8);
    float4 eb = *(const float4*)(er0 + lane * 8 + 4);
    float se0 = ea.x*ea.x + ea.y*ea.y + ea.z*ea.z + ea.w*ea.w
              + eb.x*eb.x + eb.y*eb.y + eb.z*eb.z + eb.w*eb.w;
    #pragma unroll
    for (int off = 32; off; off >>= 1) se0 += __shfl_xor(se0, off);
    float inm0 = 1.0f / fmaxf(sqrtf(se0), 1e-12f);
    float* orow = out + ((size_t)(b*NN + n))*EDIM + f*CC;
    ea.x *= inm0; ea.y *= inm0; ea.z *= inm0; ea.w *= inm0;
    eb.x *= inm0; eb.y *= inm0; eb.z *= inm0; eb.w *= inm0;
    *(float4*)(orow + lane * 8) = ea;
    *(float4*)(orow + lane * 8 + 4) = eb;
    float s1 = za.x*za.x + za.y*za.y + za.z*za.z + za.w*za.w
             + zb.x*zb.x + zb.y*zb.y + zb.z*zb.z + zb.w*zb.w;
    float s2 = za.x*ea.x + za.y*ea.y + za.z*ea.z + za.w*ea.w
             + zb.x*eb.x + zb.y*eb.y + zb.z*eb.z + zb.w*eb.w;
    #pragma unroll
    for (int off = 32; off; off >>= 1) {
        s1 += __shfl_xor(s1, off);
        s2 += __shfl_xor(s2, off);
    }
    if (lane == 0) {
        float cosv = s2 / fmaxf(sqrtf(s1), 1e-12f);   // zn . z_q
        loss_tok[t] = 2.0f - 2.0f * cosv;
        out[OUT_IDX + t] = (float)idxb;               // indices read back as float
    }
}

// ---- K4: sum per-token losses -> out[OUT_LOSS] -----------------------------
__global__ __launch_bounds__(256) void loss_reduce(
    const float* __restrict__ loss_tok, float* __restrict__ out)
{
    int tid = threadIdx.x;
    float s = 0.f;
    #pragma unroll
    for (int h = 0; h < 32; ++h) s += loss_tok[h * 256 + tid];
    #pragma unroll
    for (int off = 32; off; off >>= 1) s += __shfl_down(s, off);
    __shared__ float part[4];
    if ((tid & 63) == 0) part[tid >> 6] = s;
    __syncthreads();
    if (tid == 0) {
        float t = part[0] + part[1] + part[2] + part[3];
        out[OUT_LOSS] = t * (1.25f / (float)OUT_LOSS);
    }
}

extern "C" void kernel_launch(void* const* d_in, const int* in_sizes, int n_in,
                              void* d_out, int out_size, void* d_ws, size_t ws_size,
                              hipStream_t stream) {
    const float* z   = (const float*)d_in[0];
    const float* emb = (const float*)d_in[1];
    float* out = (float*)d_out;

    char* ws = (char*)d_ws;
    float* norm_sq = (float*)ws;                                    // 32 KB
    float* loss_tok = (float*)(ws + 32768);                         // 32 KB
    unsigned int* cand = (unsigned int*)(ws + 65536);               // 4 MB
    short* z_hi = (short*)(ws + 65536 + (size_t)4*1024*1024);       // 8 MB
    short* e_hi = z_hi + (size_t)FCB * NE * CC;                     // 8 MB
    // ws needed: ~20.1 MB

    pack_init<<<4608, 256, 0, stream>>>(z, emb, z_hi, e_hi, norm_sq);
    gemm_sel<<<dim3(NE/128, NE/128, FCB), 256, 0, stream>>>(z_hi, e_hi, norm_sq, cand);
    rescore_epilogue<<<TOKENS/4, 256, 0, stream>>>(z, emb, cand, out, loss_tok);
    loss_reduce<<<1, 256, 0, stream>>>(loss_tok, out);
}

// Round 9
// 146.194 us; speedup vs baseline: 1.5886x; 1.1044x over previous
//
#include <hip/hip_runtime.h>
#include <hip/hip_bf16.h>
#include <stdint.h>

// Problem constants (fixed by setup_inputs)
#define FCB 2            // codebooks
#define BB 16            // batch
#define NN 256           // tokens per (b)
#define EDIM 1024
#define CC 512           // channels per codebook
#define NE 4096          // prototypes per codebook
#define TOKENS (BB*FCB*NN)   // 8192
#define ROWS (FCB*NE)        // 8192 emb rows
#define OUT_LOSS (BB*NN*EDIM)   // 4194304 (also the element count for the mean)
#define OUT_IDX  (OUT_LOSS + 1)
#define MARGIN 0.15f     // rescore margin, v-units; validated R5-R8 (indices exact)

typedef __attribute__((ext_vector_type(8))) short bf16x8;   // MFMA A/B frag (4 VGPRs)
typedef __attribute__((ext_vector_type(4))) float f32x4;    // 16x16 MFMA C/D frag

// monotonic float<->uint mapping for packed argmax
__device__ __forceinline__ unsigned int ford(float v) {
    unsigned int u = __float_as_uint(v);
    return (u & 0x80000000u) ? ~u : (u | 0x80000000u);
}
__device__ __forceinline__ float unford(unsigned int u) {
    unsigned int b = (u & 0x80000000u) ? (u & 0x7fffffffu) : ~u;
    return __uint_as_float(b);
}

// ---------------------------------------------------------------------------
// ws layout:
//   [0]       norm_sq   8192 f32  (32 KB)          (written by K1 norm blocks)
//   [32768]   loss_tok  8192 f32  (32 KB)
//   [65536]   cand      8192 tok x 64 slots x 2 u32 (4 MB) top-2 per 64-col group
//   [+4MB]    z_hi      2*4096*512 bf16             (8 MB) 16-row-chunk packed
//   [+8MB]    e_hi      2*4096*512 bf16             (8 MB)
// Packed layout (R3/R5/R6-proven): elem = ((f*256 + R)*64 + Q)*128 + m*8 + j
//   (R = 16-row tile, Q = 8-elem k-chunk, m = row-in-tile, j = elem).
//   One 1-KB staging chunk = (R, qb..qb+3) = 16 rows x 32 k; both the
//   global_load_lds staging and ds_read_b128 fragment reads are lane-linear
//   (lane <-> 16 B), conflict-free.
//
// NOTE (R7 lesson): no device-scope fences / completion counters inside
// output-writing kernels — per-block write drain cost ~90 µs. Loss is
// finalized by a separate 1-block kernel.
// NOTE (R8 lesson): keep 16x16 MFMA — its C/D layout resolves 4 rows per
// width-16 merge chain (64 shuffle-steps/wave) vs 2 rows per width-32 chain
// for 32x32 (160 steps/wave); LDS-bytes/FLOP is set by the wave tile, not
// the MFMA shape, so 32x32 buys nothing here.
// ---------------------------------------------------------------------------

// ---- K1: pack z/emb -> bf16 fragment chunks; emb row norms -----------------
__global__ __launch_bounds__(256) void pack_init(
    const float* __restrict__ z, const float* __restrict__ emb,
    short* __restrict__ z_hi, short* __restrict__ e_hi,
    float* __restrict__ norm_sq)
{
    __shared__ float red[256];
    int bid = blockIdx.x;
    int tid = threadIdx.x;

    if (bid < 4096) {
        // ---- pack branch (R3/R5/R6-proven 16-row chunk indexing) ----
        bool is_emb = (bid >= 2048);
        const float* src; short* hi; int RS, FRO, FCO;
        if (!is_emb) { src = z;   hi = z_hi; RS = EDIM; FRO = 0;  FCO = CC; }
        else         { src = emb; hi = e_hi; RS = CC;   FRO = NE; FCO = 0; }
        int u = (bid & 2047) * 256 + tid;         // [0, 524288)
        int m = u & 15;
        int Q = (u >> 4) & 63;
        int R = (u >> 10) & 255;
        int f = u >> 18;
        int row = R * 16 + m;
        const float* s = src + (size_t)(f * FRO + row) * RS + f * FCO + Q * 8;
        float4 v0 = *(const float4*)s;
        float4 v1 = *(const float4*)(s + 4);
        float vv[8] = {v0.x, v0.y, v0.z, v0.w, v1.x, v1.y, v1.z, v1.w};
        bf16x8 h8;
        #pragma unroll
        for (int j = 0; j < 8; ++j) {
            __hip_bfloat16 hb = __float2bfloat16(vv[j]);
            h8[j] = *(short*)&hb;
        }
        *(bf16x8*)(hi + (size_t)u * 8) = h8;
    } else {
        // ---- norm branch: 512 blocks x 16 emb rows, no atomics ----
        int nb = bid - 4096;                      // [0, 512)
        int row_l = tid >> 4;                     // 0..15
        int seg   = tid & 15;                     // 0..15, 32 floats each
        int r = nb * 16 + row_l;                  // global emb row
        const float* p = emb + (size_t)r * CC + seg * 32;
        float ss = 0.f;
        #pragma unroll
        for (int h = 0; h < 8; ++h) {
            float4 v = *(const float4*)(p + h * 4);
            ss = fmaf(v.x, v.x, fmaf(v.y, v.y, fmaf(v.z, v.z, fmaf(v.w, v.w, ss))));
        }
        red[tid] = ss;
        __syncthreads();
        if (tid < 16) {
            float t = 0.f;
            #pragma unroll
            for (int k = 0; k < 16; ++k) t += red[tid * 16 + k];
            norm_sq[nb * 16 + tid] = t;
        }
    }
}

// ---- K2: 1-product bf16 MFMA GEMM (16x16x32, BK=64) + top-2 selection ------
// 128x128 block, 4 waves (2x2), wave = 64x64 = 4x4 tiles of 16x16x32.
// (R6-proven: 51.5 µs, MfmaUtil 27%, conflicts 0.)
__global__ __launch_bounds__(256, 3) void gemm_sel(
    const short* __restrict__ zh, const short* __restrict__ eh,
    const float* __restrict__ norm_sq, unsigned int* __restrict__ cand)
{
    __shared__ char smem[32768];      // A 16K | B 16K, chunk c at c*1024
    const int f  = blockIdx.z;
    const int t0 = blockIdx.y * 128;  // token base within codebook
    const int m0 = blockIdx.x * 128;  // proto base within codebook
    const int tid  = threadIdx.x;
    const int wave = tid >> 6, lane = tid & 63;
    const int wm = wave & 1, wn = wave >> 1;

    f32x4 acc[4][4] = {};

    for (int step = 0; step < 8; ++step) {
        __syncthreads();              // previous compute done before overwrite
        // 32 chunks of 1 KB per step: A (c<16), B (c>=16); wave stages 8
        #pragma unroll
        for (int i = 0; i < 8; ++i) {
            int c = wave * 8 + i;
            const short* gsrc = (c < 16) ? zh : eh;
            int cl = c & 15;
            int Rl = cl >> 1, h = cl & 1;
            int R = ((c < 16) ? (t0 >> 4) : (m0 >> 4)) + Rl;
            int qb = step * 8 + h * 4;
            const short* g = gsrc
                + (((size_t)f * 256 + R) * 64 + qb) * 128 + (size_t)lane * 8;
            __builtin_amdgcn_global_load_lds(
                (const __attribute__((address_space(1))) void*)g,
                (__attribute__((address_space(3))) void*)(smem + c * 1024),
                16, 0, 0);
        }
        __syncthreads();              // staged data visible to all waves

        #pragma unroll
        for (int h = 0; h < 2; ++h) {
            bf16x8 ah[4], bh[4];
            #pragma unroll
            for (int i = 0; i < 4; ++i) {
                ah[i] = *(const bf16x8*)(smem + ((wm*4 + i)*2 + h) * 1024 + lane * 16);
                bh[i] = *(const bf16x8*)(smem + 16384 + ((wn*4 + i)*2 + h) * 1024 + lane * 16);
            }
            #pragma unroll
            for (int i = 0; i < 4; ++i)
                #pragma unroll
                for (int j2 = 0; j2 < 4; ++j2)
                    acc[i][j2] = __builtin_amdgcn_mfma_f32_16x16x32_bf16(ah[i], bh[j2], acc[i][j2], 0, 0, 0);
        }
    }

    // ---- selection epilogue: per token, top-2 over this wave's 64 cols ----
    // C/D layout (16x16x32): col = lane&15, row = (lane>>4)*4 + reg
    float inm[4]; unsigned ccode[4];
    #pragma unroll
    for (int j2 = 0; j2 < 4; ++j2) {
        int col = j2 * 16 + (lane & 15);          // [0,64) within wave group
        ccode[j2] = (unsigned)(col ^ 63);
        inm[j2] = rsqrtf(norm_sq[f * NE + m0 + wn * 64 + col]);
    }

    #pragma unroll
    for (int i = 0; i < 4; ++i) {
        #pragma unroll
        for (int r = 0; r < 4; ++r) {
            unsigned p1 = 0u, p2 = 0u;
            #pragma unroll
            for (int j2 = 0; j2 < 4; ++j2) {
                float w = acc[i][j2][r] * inm[j2];
                unsigned pw = (ford(w) & 0xFFFFFFC0u) | ccode[j2];
                if (pw > p1) { p2 = p1; p1 = pw; }
                else if (pw > p2) p2 = pw;
            }
            // merge top-2 across the 16 contiguous lanes of this token row
            #pragma unroll
            for (int off = 8; off; off >>= 1) {
                unsigned q1 = __shfl_down(p1, off, 16);
                unsigned q2 = __shfl_down(p2, off, 16);
                if (q1 > p1) { unsigned t = p1; p1 = q1; p2 = (t > q2) ? t : q2; }
                else         { p2 = (p2 > q1) ? p2 : q1; }
            }
            if ((lane & 15) == 0) {
                int u = t0 + wm * 64 + i * 16 + (lane >> 4) * 4 + r;
                int b = u >> 8, n = u & 255;
                int gt = ((b * FCB + f) << 8) + n;   // global token id (b,f,n)
                int s = (blockIdx.x << 1) | wn;      // slot covers cols s*64..
                uint2 val; val.x = p1; val.y = p2;
                *(uint2*)(cand + ((size_t)gt << 7) + (s << 1)) = val;
            }
        }
    }
}

// ---- K3: rescore + outputs + per-token loss (NO atomics, NO fences) --------
__global__ __launch_bounds__(256) void rescore_epilogue(
    const float* __restrict__ z, const float* __restrict__ emb,
    const unsigned int* __restrict__ cand,
    float* __restrict__ out, float* __restrict__ loss_tok)
{
    int t = blockIdx.x * 4 + (threadIdx.x >> 6);   // global token (b,f,n)
    int lane = threadIdx.x & 63;
    int n = t & 255;
    int f = (t >> 8) & 1;
    int b = t >> 9;
    const float* zrow = z + ((size_t)(b*NN + n))*EDIM + f*CC;
    float4 za = *(const float4*)(zrow + lane * 8);
    float4 zb = *(const float4*)(zrow + lane * 8 + 4);

    // 128 candidates: lane reads slot s == lane (2 packed u32)
    uint2 cc = *(const uint2*)(cand + ((size_t)t << 7) + (lane << 1));
    unsigned c1 = cc.x, c2 = cc.y;

    unsigned m1 = (c1 > c2) ? c1 : c2;
    #pragma unroll
    for (int off = 32; off; off >>= 1) {
        unsigned o = __shfl_xor(m1, off);
        if (o > m1) m1 = o;
    }
    float thr = unford(m1) - MARGIN;

    unsigned long long bestp = 0ull;
    #pragma unroll
    for (int rnd = 0; rnd < 2; ++rnd) {
        unsigned u = rnd ? c2 : c1;
        float v = unford(u);
        unsigned long long mask = __ballot(v > thr);
        while (mask) {
            int src = __ffsll((long long)mask) - 1;
            mask &= mask - 1;
            unsigned cu = __shfl(u, src);
            int idx = (src << 6) | ((int)(cu & 63u) ^ 63);   // proto index [0,4096)
            const float* er = emb + ((size_t)(f * NE + idx)) * CC;
            float4 ea = *(const float4*)(er + lane * 8);
            float4 eb = *(const float4*)(er + lane * 8 + 4);
            float d  = za.x*ea.x + za.y*ea.y + za.z*ea.z + za.w*ea.w
                     + zb.x*eb.x + zb.y*eb.y + zb.z*eb.z + zb.w*eb.w;
            float se = ea.x*ea.x + ea.y*ea.y + ea.z*ea.z + ea.w*ea.w
                     + eb.x*eb.x + eb.y*eb.y + eb.z*eb.z + eb.w*eb.w;
            #pragma unroll
            for (int off = 32; off; off >>= 1) {
                d  += __shfl_xor(d, off);
                se += __shfl_xor(se, off);
            }
            float vex = d / fmaxf(sqrtf(se), 1e-12f);        // exact score
            unsigned long long pex = ((unsigned long long)ford(vex) << 32)
                                   | (unsigned int)(~(unsigned int)idx);
            if (pex > bestp) bestp = pex;
        }
    }
    int idxb = (int)(~(unsigned int)bestp);    // exact argmax (tie -> lower idx)

    // ---- output: z_q gather (codebook-0 row, faithful quirk) + loss -------
    const float* er0 = emb + (size_t)idxb * CC;
    float4 ea = *(const float4*)(er0 + lane * 8);
    float4 eb = *(const float4*)(er0 + lane * 8 + 4);
    float se0 = ea.x*ea.x + ea.y*ea.y + ea.z*ea.z + ea.w*ea.w
              + eb.x*eb.x + eb.y*eb.y + eb.z*eb.z + eb.w*eb.w;
    #pragma unroll
    for (int off = 32; off; off >>= 1) se0 += __shfl_xor(se0, off);
    float inm0 = 1.0f / fmaxf(sqrtf(se0), 1e-12f);
    float* orow = out + ((size_t)(b*NN + n))*EDIM + f*CC;
    ea.x *= inm0; ea.y *= inm0; ea.z *= inm0; ea.w *= inm0;
    eb.x *= inm0; eb.y *= inm0; eb.z *= inm0; eb.w *= inm0;
    *(float4*)(orow + lane * 8) = ea;
    *(float4*)(orow + lane * 8 + 4) = eb;
    float s1 = za.x*za.x + za.y*za.y + za.z*za.z + za.w*za.w
             + zb.x*zb.x + zb.y*zb.y + zb.z*zb.z + zb.w*zb.w;
    float s2 = za.x*ea.x + za.y*ea.y + za.z*ea.z + za.w*ea.w
             + zb.x*eb.x + zb.y*eb.y + zb.z*eb.z + zb.w*eb.w;
    #pragma unroll
    for (int off = 32; off; off >>= 1) {
        s1 += __shfl_xor(s1, off);
        s2 += __shfl_xor(s2, off);
    }
    if (lane == 0) {
        float cosv = s2 / fmaxf(sqrtf(s1), 1e-12f);   // zn . z_q
        loss_tok[t] = 2.0f - 2.0f * cosv;
        out[OUT_IDX + t] = (float)idxb;               // indices read back as float
    }
}

// ---- K4: sum per-token losses -> out[OUT_LOSS] -----------------------------
__global__ __launch_bounds__(256) void loss_reduce(
    const float* __restrict__ loss_tok, float* __restrict__ out)
{
    int tid = threadIdx.x;
    float s = 0.f;
    #pragma unroll
    for (int h = 0; h < 32; ++h) s += loss_tok[h * 256 + tid];
    #pragma unroll
    for (int off = 32; off; off >>= 1) s += __shfl_down(s, off);
    __shared__ float part[4];
    if ((tid & 63) == 0) part[tid >> 6] = s;
    __syncthreads();
    if (tid == 0) {
        float t = part[0] + part[1] + part[2] + part[3];
        out[OUT_LOSS] = t * (1.25f / (float)OUT_LOSS);
    }
}

extern "C" void kernel_launch(void* const* d_in, const int* in_sizes, int n_in,
                              void* d_out, int out_size, void* d_ws, size_t ws_size,
                              hipStream_t stream) {
    const float* z   = (const float*)d_in[0];
    const float* emb = (const float*)d_in[1];
    float* out = (float*)d_out;

    char* ws = (char*)d_ws;
    float* norm_sq = (float*)ws;                                    // 32 KB
    float* loss_tok = (float*)(ws + 32768);                         // 32 KB
    unsigned int* cand = (unsigned int*)(ws + 65536);               // 4 MB
    short* z_hi = (short*)(ws + 65536 + (size_t)4*1024*1024);       // 8 MB
    short* e_hi = z_hi + (size_t)FCB * NE * CC;                     // 8 MB
    // ws needed: ~20.1 MB

    pack_init<<<4608, 256, 0, stream>>>(z, emb, z_hi, e_hi, norm_sq);
    gemm_sel<<<dim3(NE/128, NE/128, FCB), 256, 0, stream>>>(z_hi, e_hi, norm_sq, cand);
    rescore_epilogue<<<TOKENS/4, 256, 0, stream>>>(z, emb, cand, out, loss_tok);
    loss_reduce<<<1, 256, 0, stream>>>(loss_tok, out);
}